// Round 8
// baseline (96.393 us; speedup 1.0000x reference)
//
#include <hip/hip_runtime.h>
#include <cstdint>
#include <cstddef>

#define BATCH  8
#define SEQ    4096
#define CHN    256        // channels (OUT)
#define NQ     768        // 3*OUT
#define KTOT   512        // WIN*IN
#define TS     128        // scan chunk length
#define NCHUNK (SEQ/TS)   // 32
#define SROW   4097       // padded rows per batch in Xbf (row 0 = zeros)

typedef __attribute__((ext_vector_type(8))) __bf16    bf16x8;
typedef __attribute__((ext_vector_type(4))) float     f32x4;
typedef __attribute__((ext_vector_type(4))) _Float16  f16x4;
typedef __attribute__((ext_vector_type(2))) _Float16  f16x2;

#define AS1(p) ((const __attribute__((address_space(1))) void*)(p))
#define AS3(p) ((__attribute__((address_space(3))) void*)(p))

// ---------------------------------------------------------------------------
// K0a: W (fp32 [768][512]) -> frag-major bf16 planes:
//      Wt[(t32*4+g)*768 + n][j] = bf16(W[n][t32*32 + g*8 + j]), t32<16,g<4,j<8
// ---------------------------------------------------------------------------
__global__ __launch_bounds__(256) void k_convW(const float* __restrict__ W,
                                               __bf16* __restrict__ Wt) {
    int lin = blockIdx.x * 256 + threadIdx.x;   // 0 .. 49151
    int n  = lin % NQ;
    int tg = lin / NQ;
    const float* src = W + (size_t)n * KTOT + tg * 8;
    float4 a = *(const float4*)(src);
    float4 b = *(const float4*)(src + 4);
    bf16x8 h;
    h[0]=(__bf16)a.x; h[1]=(__bf16)a.y; h[2]=(__bf16)a.z; h[3]=(__bf16)a.w;
    h[4]=(__bf16)b.x; h[5]=(__bf16)b.y; h[6]=(__bf16)b.z; h[7]=(__bf16)b.w;
    *(bf16x8*)(Wt + (size_t)lin * 8) = h;
}

// ---------------------------------------------------------------------------
// K0b: x (fp32 [8][4096][256]) -> Xbf ([8][4097][256] bf16, row 0 = zeros)
// ---------------------------------------------------------------------------
__global__ __launch_bounds__(256) void k_convX(const float* __restrict__ x,
                                               __bf16* __restrict__ Xb) {
    int c = blockIdx.x * 256 + threadIdx.x;
    if (c < 8 * 32) {
        int bz = c >> 5, j = c & 31;
        bf16x8 zz = {};
        *(bf16x8*)(Xb + (size_t)bz * SROW * 256 + j * 8) = zz;
    }
    int bi = c >> 17;
    int r  = c & 131071;
    int s  = r >> 5;
    int j  = r & 31;
    const float* src = x + ((size_t)bi * SEQ + s) * 256 + j * 8;
    float4 a = *(const float4*)(src);
    float4 b = *(const float4*)(src + 4);
    bf16x8 h;
    h[0]=(__bf16)a.x; h[1]=(__bf16)a.y; h[2]=(__bf16)a.z; h[3]=(__bf16)a.w;
    h[4]=(__bf16)b.x; h[5]=(__bf16)b.y; h[6]=(__bf16)b.z; h[7]=(__bf16)b.w;
    *(bf16x8*)(Xb + ((size_t)bi * SROW + 1 + s) * 256 + j * 8) = h;
}

__device__ __forceinline__ float fast_sigmoid(float y) {
    float e = __expf(-y);
    return __builtin_amdgcn_rcpf(1.f + e);
}
__device__ __forceinline__ float fast_tanh(float y) {
    float e = __expf(-2.f * y);
    return __builtin_amdgcn_rcpf(1.f + e) * 2.f - 1.f;
}

// ---------------------------------------------------------------------------
// K1: GEMM (y^T = W * xw^T) + activations — faithful m97-structure port.
//  - block 256 thr = 4 waves (2 s-halves x 2 n-halves); block tile 128s x 128n
//    wave tile 64x64 -> acc 4x4 frags = 64 AGPR (m97 geometry).
//  - K loop: 8 steps of K=64; per step stage X 16KB + W 16KB via
//    global_load_lds into a SINGLE 32KB buffer; 2 barriers per step.
//    Stall-hiding comes from 4 co-resident independent blocks/CU
//    (LDS 4x32KB=128KB, launch_bounds(256,4) caps regs at <=192 unified).
//  - X tile XOR-swizzled (pre-swizzled global source, rule #21); W tile
//    linear (frag reads are 256B-contiguous per 16-lane phase: conflict-free).
//  - epilogue: per-wave LDS transpose (reuses staging LDS) -> 128B stores.
// Grid = 256 s-tiles * 6 n-tiles = 1536.
// ---------------------------------------------------------------------------
__global__ __launch_bounds__(256, 4) void k_gemm(
    const __bf16* __restrict__ Xb, const __bf16* __restrict__ Wt,
    const float* __restrict__ bias,
    _Float16* __restrict__ Zb, _Float16* __restrict__ Fb, _Float16* __restrict__ Ob)
{
    __shared__ char XL[16384];   // [128 s-rows][128 B], XOR-swizzled content
    __shared__ char WL[16384];   // [8 planes][128 n][16 B], linear

    int tid = threadIdx.x;
    int bid = blockIdx.x;
    int sbt = bid / 6;           // 0..255 : s-tile (bi,sc)
    int ngt = bid % 6;           // 0..5   : n-tile of 128 (gate = ngt>>1)
    int bi  = sbt >> 5;
    int sc  = sbt & 31;
    int s0  = sc * 128;
    int wid = tid >> 6;
    int l   = tid & 63;
    int l15 = l & 15, lg = l >> 4;
    int wr  = wid >> 1;          // s-half (0/1)
    int wc  = wid & 1;           // n-half (0/1)

    f32x4 acc[4][4];
    const f32x4 vzero = {0.f, 0.f, 0.f, 0.f};
    #pragma unroll
    for (int a = 0; a < 4; ++a)
        #pragma unroll
        for (int b = 0; b < 4; ++b)
            acc[a][b] = vzero;

    // ---- K loop: 8 t-steps of K=64 ----
    #pragma unroll
    for (int t = 0; t < 8; ++t) {
        __syncthreads();                 // prev step's ds_reads retired
        // stage X: 1024 slots of 16B; slot=(row, c16); content pre-swizzled
        #pragma unroll
        for (int i = 0; i < 4; ++i) {
            int slot = i * 256 + tid;
            int row  = slot >> 3;        // 0..127 (s-local)
            int c16  = slot & 7;
            int c16g = c16 ^ (row & 7);  // inverse-swizzle the SOURCE
            const __bf16* gsrc = Xb + ((size_t)bi * SROW + s0 + row + (t >> 2)) * 256
                                    + (t & 3) * 64 + c16g * 8;
            __builtin_amdgcn_global_load_lds(AS1(gsrc), AS3(XL + slot * 16), 16, 0, 0);
        }
        // stage W: 8 planes (k-slices) x 128 n x 16B, linear
        #pragma unroll
        for (int i = 0; i < 4; ++i) {
            int slot = i * 256 + tid;
            int p  = slot >> 7;          // 0..7 plane (k = t*64 + p*8.. within)
            int nl = slot & 127;
            const __bf16* gsrc = Wt + ((size_t)(t * 8 + p) * NQ + ngt * 128 + nl) * 8;
            __builtin_amdgcn_global_load_lds(AS1(gsrc), AS3(WL + slot * 16), 16, 0, 0);
        }
        __syncthreads();                 // drains vmcnt(0): tile ready

        #pragma unroll
        for (int kk = 0; kk < 2; ++kk) {
            bf16x8 xf[4], wf[4];
            #pragma unroll
            for (int st = 0; st < 4; ++st) {
                int row = wr * 64 + st * 16 + l15;
                int byte = (row * 128 + (kk * 4 + lg) * 16) ^ ((row & 7) << 4);
                xf[st] = *(const bf16x8*)(XL + byte);
            }
            #pragma unroll
            for (int nt = 0; nt < 4; ++nt)
                wf[nt] = *(const bf16x8*)(WL + (kk * 4 + lg) * 2048
                                             + (wc * 64 + nt * 16 + l15) * 16);
            __builtin_amdgcn_s_setprio(1);
            #pragma unroll
            for (int nt = 0; nt < 4; ++nt)
                #pragma unroll
                for (int st = 0; st < 4; ++st)
                    acc[nt][st] = __builtin_amdgcn_mfma_f32_16x16x32_bf16(
                                      wf[nt], xf[st], acc[nt][st], 0, 0, 0);
            __builtin_amdgcn_s_setprio(0);
        }
    }

    __syncthreads();   // staging LDS free -> reuse as epilogue scratch

    // ---- epilogue: activation -> per-wave LDS transpose -> 128B stores ----
    int gate    = ngt >> 1;                    // 0:z 1:f 2:o
    int ch_base = (ngt & 1) * 128 + wc * 64;   // channel base (0..255)
    _Float16* buf = (gate == 0) ? Zb : (gate == 1) ? Fb : Ob;
    char* Sw = ((wid < 2) ? XL : WL) + (wid & 1) * 8192;   // 8KB per wave

    // Phase A: lane writes f16x4 (4 ch at fixed s) into swizzled scratch
    #pragma unroll
    for (int nt = 0; nt < 4; ++nt) {
        float4 bv = *(const float4*)(bias + ngt * 128 + wc * 64 + nt * 16 + lg * 4);
        #pragma unroll
        for (int st = 0; st < 4; ++st) {
            f16x4 hv;
            #pragma unroll
            for (int r = 0; r < 4; ++r) {
                float bvr = (r == 0) ? bv.x : (r == 1) ? bv.y : (r == 2) ? bv.z : bv.w;
                float y = acc[nt][st][r] + bvr;
                float v = (gate == 0) ? fast_tanh(y) : fast_sigmoid(y);
                hv[r] = (_Float16)v;
            }
            int byte = ((st * 16 + l15) * 128 + (nt * 16 + lg * 4) * 2)
                       ^ ((l15 & 7) << 4);
            *(f16x4*)(Sw + byte) = hv;
        }
    }
    // Phase B: read transposed, store 128B-contiguous per 16 lanes
    #pragma unroll
    for (int so = 0; so < 16; ++so) {
        int s_loc = so * 4 + lg;
        int byte  = (s_loc * 128 + l15 * 8) ^ ((s_loc & 7) << 4);
        f16x4 v = *(const f16x4*)(Sw + byte);
        *(f16x4*)(buf + ((size_t)bi * SEQ + s0 + wr * 64 + s_loc) * CHN
                      + ch_base + l15 * 4) = v;
    }
}

// ---------------------------------------------------------------------------
// K2: per-chunk scan summaries; thread handles 2 channels (4B f16x2 loads).
// ---------------------------------------------------------------------------
__global__ __launch_bounds__(128) void k_scan1(const _Float16* __restrict__ Fb,
                                               const _Float16* __restrict__ Zb,
                                               float* __restrict__ Aq,
                                               float* __restrict__ Bq) {
    int bi = blockIdx.x >> 5;
    int ck = blockIdx.x & 31;
    int c2 = threadIdx.x;
    size_t base = (((size_t)bi * SEQ + ck * TS) * CHN + c2 * 2) >> 1;
    const f16x2* F2 = (const f16x2*)Fb;
    const f16x2* Z2 = (const f16x2*)Zb;
    float a0 = 1.f, a1 = 1.f, c0 = 0.f, c1 = 0.f;
    #pragma unroll 8
    for (int s = 0; s < TS; ++s) {
        f16x2 f = F2[base + (size_t)s * (CHN / 2)];
        f16x2 z = Z2[base + (size_t)s * (CHN / 2)];
        float f0 = (float)f[0], f1 = (float)f[1];
        c0 = f0 * c0 + (1.f - f0) * (float)z[0];
        c1 = f1 * c1 + (1.f - f1) * (float)z[1];
        a0 *= f0; a1 *= f1;
    }
    int o = blockIdx.x * CHN + c2 * 2;
    *(float2*)(Aq + o) = make_float2(a0, a1);
    *(float2*)(Bq + o) = make_float2(c0, c1);
}

// ---------------------------------------------------------------------------
// K3: sequential carry across chunks. 8 blocks x 256 threads, 32 steps.
// ---------------------------------------------------------------------------
__global__ __launch_bounds__(256) void k_scan2(const float* __restrict__ Aq,
                                               const float* __restrict__ Bq,
                                               float* __restrict__ Cq) {
    int bi = blockIdx.x;
    int ch = threadIdx.x;
    float c = 0.f;
    #pragma unroll
    for (int ck = 0; ck < NCHUNK; ++ck) {
        int o = (bi * NCHUNK + ck) * CHN + ch;
        Cq[o] = c;
        c = Aq[o] * c + Bq[o];
    }
}

// ---------------------------------------------------------------------------
// K4: final pass — redo local scan seeded with carry, out = sigmoid(o) * c.
// ---------------------------------------------------------------------------
__global__ __launch_bounds__(128) void k_scan3(const _Float16* __restrict__ Fb,
                                               const _Float16* __restrict__ Zb,
                                               const _Float16* __restrict__ Ob,
                                               const float* __restrict__ Cq,
                                               float* __restrict__ out) {
    int bi = blockIdx.x >> 5;
    int ck = blockIdx.x & 31;
    int c2 = threadIdx.x;
    float2 c = *(const float2*)(Cq + blockIdx.x * CHN + c2 * 2);
    size_t base = (((size_t)bi * SEQ + ck * TS) * CHN + c2 * 2) >> 1;
    const f16x2* F2 = (const f16x2*)Fb;
    const f16x2* Z2 = (const f16x2*)Zb;
    const f16x2* O2 = (const f16x2*)Ob;
    float* outp = out + (((size_t)bi * SEQ + ck * TS) * CHN + c2 * 2);
    #pragma unroll 4
    for (int s = 0; s < TS; ++s) {
        f16x2 f  = F2[base + (size_t)s * (CHN / 2)];
        f16x2 z  = Z2[base + (size_t)s * (CHN / 2)];
        f16x2 so = O2[base + (size_t)s * (CHN / 2)];
        float f0 = (float)f[0], f1 = (float)f[1];
        c.x = f0 * c.x + (1.f - f0) * (float)z[0];
        c.y = f1 * c.y + (1.f - f1) * (float)z[1];
        *(float2*)(outp + (size_t)s * CHN) = make_float2((float)so[0] * c.x,
                                                         (float)so[1] * c.y);
    }
}

// ---------------------------------------------------------------------------
extern "C" void kernel_launch(void* const* d_in, const int* in_sizes, int n_in,
                              void* d_out, int out_size, void* d_ws, size_t ws_size,
                              hipStream_t stream)
{
    const float* x = (const float*)d_in[0];   // (8,4096,256) fp32
    const float* W = (const float*)d_in[1];   // (768,512)    fp32
    const float* b = (const float*)d_in[2];   // (768,)       fp32
    float* out = (float*)d_out;               // (8,4096,256) fp32

    char* ws = (char*)d_ws;
    const size_t MB = 1024 * 1024;
    _Float16* Zb = (_Float16*)(ws +  0 * MB);   // 16 MB
    _Float16* Fb = (_Float16*)(ws + 16 * MB);   // 16 MB
    _Float16* Ob = (_Float16*)(ws + 32 * MB);   // 16 MB
    __bf16*   Wt = (__bf16*)  (ws + 48 * MB);   // 768 KB
    float*    Aq = (float*)   (ws + 49 * MB);   // 256 KB
    float*    Bq = (float*)   (ws + 50 * MB);   // 256 KB
    float*    Cq = (float*)   (ws + 51 * MB);   // 256 KB
    __bf16*   Xb = (__bf16*)  (ws + 52 * MB);   // 16.02 MB

    k_convW<<<dim3(192),            dim3(256), 0, stream>>>(W, Wt);
    k_convX<<<dim3(4096),           dim3(256), 0, stream>>>(x, Xb);
    k_gemm <<<dim3(1536),           dim3(256), 0, stream>>>(Xb, Wt, b, Zb, Fb, Ob);
    k_scan1<<<dim3(BATCH * NCHUNK), dim3(128), 0, stream>>>(Fb, Zb, Aq, Bq);
    k_scan2<<<dim3(BATCH),          dim3(256), 0, stream>>>(Aq, Bq, Cq);
    k_scan3<<<dim3(BATCH * NCHUNK), dim3(128), 0, stream>>>(Fb, Zb, Ob, Cq, out);
}

// Round 9
// 82.002 us; speedup vs baseline: 1.1755x; 1.1755x over previous
//
#include <hip/hip_runtime.h>
#include <cstdint>
#include <cstddef>

#define BATCH  8
#define SEQ    4096
#define CHN    256        // channels (OUT)
#define NQ     768        // 3*OUT
#define KTOT   512        // WIN*IN
#define TS     128        // scan chunk length
#define NCHUNK (SEQ/TS)   // 32
#define SROW   4097       // padded rows per batch in Xbf (row 0 = zeros)

typedef __attribute__((ext_vector_type(8))) __bf16    bf16x8;
typedef __attribute__((ext_vector_type(4))) float     f32x4;
typedef __attribute__((ext_vector_type(4))) _Float16  f16x4;
typedef __attribute__((ext_vector_type(2))) _Float16  f16x2;

#define AS1(p) ((const __attribute__((address_space(1))) void*)(p))
#define AS3(p) ((__attribute__((address_space(3))) void*)(p))

// ---------------------------------------------------------------------------
// K0a: W (fp32 [768][512]) -> frag-major bf16 planes:
//      Wt[(t32*4+g)*768 + n][j] = bf16(W[n][t32*32 + g*8 + j]), t32<16,g<4,j<8
// ---------------------------------------------------------------------------
__global__ __launch_bounds__(256) void k_convW(const float* __restrict__ W,
                                               __bf16* __restrict__ Wt) {
    int lin = blockIdx.x * 256 + threadIdx.x;   // 0 .. 49151
    int n  = lin % NQ;
    int tg = lin / NQ;
    const float* src = W + (size_t)n * KTOT + tg * 8;
    float4 a = *(const float4*)(src);
    float4 b = *(const float4*)(src + 4);
    bf16x8 h;
    h[0]=(__bf16)a.x; h[1]=(__bf16)a.y; h[2]=(__bf16)a.z; h[3]=(__bf16)a.w;
    h[4]=(__bf16)b.x; h[5]=(__bf16)b.y; h[6]=(__bf16)b.z; h[7]=(__bf16)b.w;
    *(bf16x8*)(Wt + (size_t)lin * 8) = h;
}

// ---------------------------------------------------------------------------
// K0b: x (fp32 [8][4096][256]) -> Xbf ([8][4097][256] bf16, row 0 = zeros)
// ---------------------------------------------------------------------------
__global__ __launch_bounds__(256) void k_convX(const float* __restrict__ x,
                                               __bf16* __restrict__ Xb) {
    int c = blockIdx.x * 256 + threadIdx.x;
    if (c < 8 * 32) {
        int bz = c >> 5, j = c & 31;
        bf16x8 zz = {};
        *(bf16x8*)(Xb + (size_t)bz * SROW * 256 + j * 8) = zz;
    }
    int bi = c >> 17;
    int r  = c & 131071;
    int s  = r >> 5;
    int j  = r & 31;
    const float* src = x + ((size_t)bi * SEQ + s) * 256 + j * 8;
    float4 a = *(const float4*)(src);
    float4 b = *(const float4*)(src + 4);
    bf16x8 h;
    h[0]=(__bf16)a.x; h[1]=(__bf16)a.y; h[2]=(__bf16)a.z; h[3]=(__bf16)a.w;
    h[4]=(__bf16)b.x; h[5]=(__bf16)b.y; h[6]=(__bf16)b.z; h[7]=(__bf16)b.w;
    *(bf16x8*)(Xb + ((size_t)bi * SROW + 1 + s) * 256 + j * 8) = h;
}

__device__ __forceinline__ float fast_sigmoid(float y) {
    float e = __expf(-y);
    return __builtin_amdgcn_rcpf(1.f + e);
}
__device__ __forceinline__ float fast_tanh(float y) {
    float e = __expf(-2.f * y);
    return __builtin_amdgcn_rcpf(1.f + e) * 2.f - 1.f;
}

// ---------------------------------------------------------------------------
// K1: GEMM (y^T = W * xw^T) + activations.  R8 geometry + two fixes:
//  (a) double-buffered staging with stage(t+1)-before-compute(t) (T3-min):
//      one barrier per step, stage latency hidden under MFMA.
//  (b) XCD-pinned grid: blockIdx = i*8 + (sbt&7) so all 6 gate-blocks of an
//      s-tile run back-to-back on ONE XCD -> X fetched once per XCD.
//  Block 256 thr = 4 waves (2s x 2n); tile 128s x 128n; wave 64x64, acc 4x4.
//  LDS 2 x 32KB = 64KB -> 2 blocks/CU co-resident.
// ---------------------------------------------------------------------------
__global__ __launch_bounds__(256, 2) void k_gemm(
    const __bf16* __restrict__ Xb, const __bf16* __restrict__ Wt,
    const float* __restrict__ bias,
    _Float16* __restrict__ Zb, _Float16* __restrict__ Fb, _Float16* __restrict__ Ob)
{
    __shared__ char XL[2][16384];   // [buf][128 rows][8 c16 x 16B], swizzled
    __shared__ char WL[2][16384];   // [buf][8 planes][128 n][16B], linear

    int tid = threadIdx.x;
    int bid = blockIdx.x;
    // XCD-pinned decode: bid = i*8 + x ; x = sbt&7 ; i = (sbt>>3)*6 + ngt
    int x_  = bid & 7;
    int i_  = bid >> 3;
    int ngt = i_ % 6;            // n-tile of 128 (gate = ngt>>1)
    int sbt = (i_ / 6) * 8 + x_; // 0..255 s-tile
    int bi  = sbt >> 5;
    int sc  = sbt & 31;
    int s0  = sc * 128;
    int wid = tid >> 6;
    int l   = tid & 63;
    int l15 = l & 15, lg = l >> 4;
    int wr  = wid >> 1;          // s-half (0/1)
    int wc  = wid & 1;           // n-half (0/1)

    // stage X: 1024 slots of 16B; slot=(row,c16); source col pre-swizzled.
    // stage W: 8 planes (8-col k-groups) x 128 n x 16B, linear.
    #define STAGE(bsel, t)                                                       \
        {                                                                        \
            _Pragma("unroll")                                                    \
            for (int i2 = 0; i2 < 4; ++i2) {                                     \
                int slot = i2 * 256 + tid;                                       \
                int row  = slot >> 3;                                            \
                int c16  = slot & 7;                                             \
                int c16g = c16 ^ (row & 7);                                      \
                const __bf16* gsrc = Xb +                                        \
                    ((size_t)bi * SROW + s0 + row + ((t) >> 2)) * 256            \
                    + ((t) & 3) * 64 + c16g * 8;                                 \
                __builtin_amdgcn_global_load_lds(AS1(gsrc),                      \
                    AS3(XL[bsel] + slot * 16), 16, 0, 0);                        \
            }                                                                    \
            _Pragma("unroll")                                                    \
            for (int i2 = 0; i2 < 4; ++i2) {                                     \
                int slot = i2 * 256 + tid;                                       \
                int p  = slot >> 7;                                              \
                int nl = slot & 127;                                             \
                const __bf16* gsrc = Wt +                                        \
                    ((size_t)((t) * 8 + p) * NQ + ngt * 128 + nl) * 8;           \
                __builtin_amdgcn_global_load_lds(AS1(gsrc),                      \
                    AS3(WL[bsel] + slot * 16), 16, 0, 0);                        \
            }                                                                    \
        }

    f32x4 acc[4][4];
    const f32x4 vzero = {0.f, 0.f, 0.f, 0.f};
    #pragma unroll
    for (int a = 0; a < 4; ++a)
        #pragma unroll
        for (int b = 0; b < 4; ++b)
            acc[a][b] = vzero;

    STAGE(0, 0);
    __syncthreads();                 // buf0 ready

    // ---- K loop: 8 t-steps of K=64; stage(t+1) || compute(t); 1 barrier/t --
    #pragma unroll
    for (int t = 0; t < 8; ++t) {
        if (t < 7) STAGE((t + 1) & 1, t + 1);

        const char* Xc = XL[t & 1];
        const char* Wc = WL[t & 1];
        #pragma unroll
        for (int kk = 0; kk < 2; ++kk) {
            bf16x8 xf[4], wf[4];
            #pragma unroll
            for (int st = 0; st < 4; ++st) {
                int row = wr * 64 + st * 16 + l15;
                int byte = (row * 128 + (kk * 4 + lg) * 16) ^ ((row & 7) << 4);
                xf[st] = *(const bf16x8*)(Xc + byte);
            }
            #pragma unroll
            for (int nt = 0; nt < 4; ++nt)
                wf[nt] = *(const bf16x8*)(Wc + (kk * 4 + lg) * 2048
                                             + (wc * 64 + nt * 16 + l15) * 16);
            __builtin_amdgcn_s_setprio(1);
            #pragma unroll
            for (int nt = 0; nt < 4; ++nt)
                #pragma unroll
                for (int st = 0; st < 4; ++st)
                    acc[nt][st] = __builtin_amdgcn_mfma_f32_16x16x32_bf16(
                                      wf[nt], xf[st], acc[nt][st], 0, 0, 0);
            __builtin_amdgcn_s_setprio(0);
        }
        __syncthreads();             // t+1 staged; buf(t&1) reads retired
    }

    // ---- epilogue: activation -> per-wave LDS transpose -> 128B stores ----
    int gate    = ngt >> 1;                    // 0:z 1:f 2:o
    int ch_base = (ngt & 1) * 128 + wc * 64;   // channel base (0..255)
    _Float16* buf = (gate == 0) ? Zb : (gate == 1) ? Fb : Ob;
    char* Sw = (char*)XL + wid * 8192;         // 8KB per-wave scratch

    #pragma unroll
    for (int nt = 0; nt < 4; ++nt) {
        float4 bv = *(const float4*)(bias + ngt * 128 + wc * 64 + nt * 16 + lg * 4);
        #pragma unroll
        for (int st = 0; st < 4; ++st) {
            f16x4 hv;
            #pragma unroll
            for (int r = 0; r < 4; ++r) {
                float bvr = (r == 0) ? bv.x : (r == 1) ? bv.y : (r == 2) ? bv.z : bv.w;
                float y = acc[nt][st][r] + bvr;
                float v = (gate == 0) ? fast_tanh(y) : fast_sigmoid(y);
                hv[r] = (_Float16)v;
            }
            int byte = ((st * 16 + l15) * 128 + (nt * 16 + lg * 4) * 2)
                       ^ ((l15 & 7) << 4);
            *(f16x4*)(Sw + byte) = hv;
        }
    }
    #pragma unroll
    for (int so = 0; so < 16; ++so) {
        int s_loc = so * 4 + lg;
        int byte  = (s_loc * 128 + l15 * 8) ^ ((s_loc & 7) << 4);
        f16x4 v = *(const f16x4*)(Sw + byte);
        *(f16x4*)(buf + ((size_t)bi * SEQ + s0 + wr * 64 + s_loc) * CHN
                      + ch_base + l15 * 4) = v;
    }
}

// ---------------------------------------------------------------------------
// K2: per-chunk scan summaries; thread handles 2 channels (4B f16x2 loads).
// ---------------------------------------------------------------------------
__global__ __launch_bounds__(128) void k_scan1(const _Float16* __restrict__ Fb,
                                               const _Float16* __restrict__ Zb,
                                               float* __restrict__ Aq,
                                               float* __restrict__ Bq) {
    int bi = blockIdx.x >> 5;
    int ck = blockIdx.x & 31;
    int c2 = threadIdx.x;
    size_t base = (((size_t)bi * SEQ + ck * TS) * CHN + c2 * 2) >> 1;
    const f16x2* F2 = (const f16x2*)Fb;
    const f16x2* Z2 = (const f16x2*)Zb;
    float a0 = 1.f, a1 = 1.f, c0 = 0.f, c1 = 0.f;
    #pragma unroll 8
    for (int s = 0; s < TS; ++s) {
        f16x2 f = F2[base + (size_t)s * (CHN / 2)];
        f16x2 z = Z2[base + (size_t)s * (CHN / 2)];
        float f0 = (float)f[0], f1 = (float)f[1];
        c0 = f0 * c0 + (1.f - f0) * (float)z[0];
        c1 = f1 * c1 + (1.f - f1) * (float)z[1];
        a0 *= f0; a1 *= f1;
    }
    int o = blockIdx.x * CHN + c2 * 2;
    *(float2*)(Aq + o) = make_float2(a0, a1);
    *(float2*)(Bq + o) = make_float2(c0, c1);
}

// ---------------------------------------------------------------------------
// K3: sequential carry across chunks. 8 blocks x 256 threads, 32 steps.
// ---------------------------------------------------------------------------
__global__ __launch_bounds__(256) void k_scan2(const float* __restrict__ Aq,
                                               const float* __restrict__ Bq,
                                               float* __restrict__ Cq) {
    int bi = blockIdx.x;
    int ch = threadIdx.x;
    float c = 0.f;
    #pragma unroll
    for (int ck = 0; ck < NCHUNK; ++ck) {
        int o = (bi * NCHUNK + ck) * CHN + ch;
        Cq[o] = c;
        c = Aq[o] * c + Bq[o];
    }
}

// ---------------------------------------------------------------------------
// K4: final pass — redo local scan seeded with carry, out = sigmoid(o) * c.
// ---------------------------------------------------------------------------
__global__ __launch_bounds__(128) void k_scan3(const _Float16* __restrict__ Fb,
                                               const _Float16* __restrict__ Zb,
                                               const _Float16* __restrict__ Ob,
                                               const float* __restrict__ Cq,
                                               float* __restrict__ out) {
    int bi = blockIdx.x >> 5;
    int ck = blockIdx.x & 31;
    int c2 = threadIdx.x;
    float2 c = *(const float2*)(Cq + blockIdx.x * CHN + c2 * 2);
    size_t base = (((size_t)bi * SEQ + ck * TS) * CHN + c2 * 2) >> 1;
    const f16x2* F2 = (const f16x2*)Fb;
    const f16x2* Z2 = (const f16x2*)Zb;
    const f16x2* O2 = (const f16x2*)Ob;
    float* outp = out + (((size_t)bi * SEQ + ck * TS) * CHN + c2 * 2);
    #pragma unroll 4
    for (int s = 0; s < TS; ++s) {
        f16x2 f  = F2[base + (size_t)s * (CHN / 2)];
        f16x2 z  = Z2[base + (size_t)s * (CHN / 2)];
        f16x2 so = O2[base + (size_t)s * (CHN / 2)];
        float f0 = (float)f[0], f1 = (float)f[1];
        c.x = f0 * c.x + (1.f - f0) * (float)z[0];
        c.y = f1 * c.y + (1.f - f1) * (float)z[1];
        *(float2*)(outp + (size_t)s * CHN) = make_float2((float)so[0] * c.x,
                                                         (float)so[1] * c.y);
    }
}

// ---------------------------------------------------------------------------
extern "C" void kernel_launch(void* const* d_in, const int* in_sizes, int n_in,
                              void* d_out, int out_size, void* d_ws, size_t ws_size,
                              hipStream_t stream)
{
    const float* x = (const float*)d_in[0];   // (8,4096,256) fp32
    const float* W = (const float*)d_in[1];   // (768,512)    fp32
    const float* b = (const float*)d_in[2];   // (768,)       fp32
    float* out = (float*)d_out;               // (8,4096,256) fp32

    char* ws = (char*)d_ws;
    const size_t MB = 1024 * 1024;
    _Float16* Zb = (_Float16*)(ws +  0 * MB);   // 16 MB
    _Float16* Fb = (_Float16*)(ws + 16 * MB);   // 16 MB
    _Float16* Ob = (_Float16*)(ws + 32 * MB);   // 16 MB
    __bf16*   Wt = (__bf16*)  (ws + 48 * MB);   // 768 KB
    float*    Aq = (float*)   (ws + 49 * MB);   // 256 KB
    float*    Bq = (float*)   (ws + 50 * MB);   // 256 KB
    float*    Cq = (float*)   (ws + 51 * MB);   // 256 KB
    __bf16*   Xb = (__bf16*)  (ws + 52 * MB);   // 16.02 MB

    k_convW<<<dim3(192),            dim3(256), 0, stream>>>(W, Wt);
    k_convX<<<dim3(4096),           dim3(256), 0, stream>>>(x, Xb);
    k_gemm <<<dim3(1536),           dim3(256), 0, stream>>>(Xb, Wt, b, Zb, Fb, Ob);
    k_scan1<<<dim3(BATCH * NCHUNK), dim3(128), 0, stream>>>(Fb, Zb, Aq, Bq);
    k_scan2<<<dim3(BATCH),          dim3(256), 0, stream>>>(Aq, Bq, Cq);
    k_scan3<<<dim3(BATCH * NCHUNK), dim3(128), 0, stream>>>(Fb, Zb, Ob, Cq, out);
}

// Round 10
// 78.724 us; speedup vs baseline: 1.2244x; 1.0416x over previous
//
#include <hip/hip_runtime.h>
#include <cstdint>
#include <cstddef>

#define BATCH  8
#define SEQ    4096
#define CHN    256        // channels (OUT)
#define NQ     768        // 3*OUT
#define KTOT   512        // WIN*IN
#define TS     128        // scan chunk length
#define NCHUNK (SEQ/TS)   // 32
#define SROW   4097       // padded rows per batch in Xbf (row 0 = zeros)

typedef __attribute__((ext_vector_type(8))) __bf16    bf16x8;
typedef __attribute__((ext_vector_type(4))) float     f32x4;
typedef __attribute__((ext_vector_type(4))) _Float16  f16x4;
typedef __attribute__((ext_vector_type(2))) _Float16  f16x2;

#define AS1(p) ((const __attribute__((address_space(1))) void*)(p))
#define AS3(p) ((__attribute__((address_space(3))) void*)(p))

// ---------------------------------------------------------------------------
// K0a: W (fp32 [768][512]) -> frag-major bf16 planes:
//      Wt[tg*768 + n][j] = bf16(W[n][tg*8 + j]),  tg<64, j<8
// ---------------------------------------------------------------------------
__global__ __launch_bounds__(256) void k_convW(const float* __restrict__ W,
                                               __bf16* __restrict__ Wt) {
    int lin = blockIdx.x * 256 + threadIdx.x;   // 0 .. 49151
    int n  = lin % NQ;
    int tg = lin / NQ;
    const float* src = W + (size_t)n * KTOT + tg * 8;
    float4 a = *(const float4*)(src);
    float4 b = *(const float4*)(src + 4);
    bf16x8 h;
    h[0]=(__bf16)a.x; h[1]=(__bf16)a.y; h[2]=(__bf16)a.z; h[3]=(__bf16)a.w;
    h[4]=(__bf16)b.x; h[5]=(__bf16)b.y; h[6]=(__bf16)b.z; h[7]=(__bf16)b.w;
    *(bf16x8*)(Wt + (size_t)lin * 8) = h;
}

// ---------------------------------------------------------------------------
// K0b: x (fp32 [8][4096][256]) -> Xbf ([8][4097][256] bf16, row 0 = zeros)
// ---------------------------------------------------------------------------
__global__ __launch_bounds__(256) void k_convX(const float* __restrict__ x,
                                               __bf16* __restrict__ Xb) {
    int c = blockIdx.x * 256 + threadIdx.x;
    if (c < 8 * 32) {
        int bz = c >> 5, j = c & 31;
        bf16x8 zz = {};
        *(bf16x8*)(Xb + (size_t)bz * SROW * 256 + j * 8) = zz;
    }
    int bi = c >> 17;
    int r  = c & 131071;
    int s  = r >> 5;
    int j  = r & 31;
    const float* src = x + ((size_t)bi * SEQ + s) * 256 + j * 8;
    float4 a = *(const float4*)(src);
    float4 b = *(const float4*)(src + 4);
    bf16x8 h;
    h[0]=(__bf16)a.x; h[1]=(__bf16)a.y; h[2]=(__bf16)a.z; h[3]=(__bf16)a.w;
    h[4]=(__bf16)b.x; h[5]=(__bf16)b.y; h[6]=(__bf16)b.z; h[7]=(__bf16)b.w;
    *(bf16x8*)(Xb + ((size_t)bi * SROW + 1 + s) * 256 + j * 8) = h;
}

__device__ __forceinline__ float fast_sigmoid(float y) {
    float e = __expf(-y);
    return __builtin_amdgcn_rcpf(1.f + e);
}
__device__ __forceinline__ float fast_tanh(float y) {
    float e = __expf(-2.f * y);
    return __builtin_amdgcn_rcpf(1.f + e) * 2.f - 1.f;
}

// ---------------------------------------------------------------------------
// K1: GEMM (y^T = W * xw^T) + activations.  R9 + m97-granularity:
//  - BK=32: 16 t-steps, 16 MFMA/wave/step; W staged 8KB/step (double-buf);
//    X staged 16KB per TWO steps (K=64-pitch tile, 2-deep pair buffer).
//  - LDS 48KB -> 3 blocks/CU co-resident; launch_bounds(256,3) caps regs.
//  - XCD-pinned grid (all 6 gate-blocks of an s-tile on one XCD).
//  Block 256 thr = 4 waves (2s x 2n); tile 128s x 128n; wave 64x64, acc 4x4.
// ---------------------------------------------------------------------------
__global__ __launch_bounds__(256, 3) void k_gemm(
    const __bf16* __restrict__ Xb, const __bf16* __restrict__ Wt,
    const float* __restrict__ bias,
    _Float16* __restrict__ Zb, _Float16* __restrict__ Fb, _Float16* __restrict__ Ob)
{
    __shared__ char XL[2][16384];   // [pairbuf][128 rows][8 c16 x 16B], swizzled
    __shared__ char WL[2][8192];    // [buf][4 planes][128 n][16B], linear

    int tid = threadIdx.x;
    int bid = blockIdx.x;
    // XCD-pinned decode: bid = i*8 + x ; x = sbt&7 ; i = (sbt>>3)*6 + ngt
    int x_  = bid & 7;
    int i_  = bid >> 3;
    int ngt = i_ % 6;            // n-tile of 128 (gate = ngt>>1)
    int sbt = (i_ / 6) * 8 + x_; // 0..255 s-tile
    int bi  = sbt >> 5;
    int sc  = sbt & 31;
    int s0  = sc * 128;
    int wid = tid >> 6;
    int l   = tid & 63;
    int l15 = l & 15, lg = l >> 4;
    int wr  = wid >> 1;          // s-half (0/1)
    int wc  = wid & 1;           // n-half (0/1)

    // X pair-tile q (covers steps 2q, 2q+1): rows s0..s0+127 (+kh), 64 cols.
    #define STAGE_X(bsel, q)                                                     \
        {                                                                        \
            _Pragma("unroll")                                                    \
            for (int i2 = 0; i2 < 4; ++i2) {                                     \
                int slot = i2 * 256 + tid;                                       \
                int row  = slot >> 3;                                            \
                int c16  = slot & 7;                                             \
                int c16g = c16 ^ (row & 7);                                      \
                const __bf16* gsrc = Xb +                                        \
                    ((size_t)bi * SROW + s0 + row + ((q) >> 2)) * 256            \
                    + ((q) & 3) * 64 + c16g * 8;                                 \
                __builtin_amdgcn_global_load_lds(AS1(gsrc),                      \
                    AS3(XL[bsel] + slot * 16), 16, 0, 0);                        \
            }                                                                    \
        }
    // W tile for step t: planes 4t..4t+3 (each 128n x 16B), linear.
    #define STAGE_W(bsel, t)                                                     \
        {                                                                        \
            _Pragma("unroll")                                                    \
            for (int i2 = 0; i2 < 2; ++i2) {                                     \
                int slot = i2 * 256 + tid;                                       \
                int p  = slot >> 7;                                              \
                int nl = slot & 127;                                             \
                const __bf16* gsrc = Wt +                                        \
                    ((size_t)((t) * 4 + p) * NQ + ngt * 128 + nl) * 8;           \
                __builtin_amdgcn_global_load_lds(AS1(gsrc),                      \
                    AS3(WL[bsel] + slot * 16), 16, 0, 0);                        \
            }                                                                    \
        }

    f32x4 acc[4][4];
    const f32x4 vzero = {0.f, 0.f, 0.f, 0.f};
    #pragma unroll
    for (int a = 0; a < 4; ++a)
        #pragma unroll
        for (int b = 0; b < 4; ++b)
            acc[a][b] = vzero;

    STAGE_X(0, 0);
    STAGE_W(0, 0);
    __syncthreads();                 // X pair 0 + W step 0 ready

    // ---- K loop: 16 t-steps of K=32; stage-ahead, 1 barrier per step ----
    #pragma unroll
    for (int t = 0; t < 16; ++t) {
        if (t < 15) {
            STAGE_W((t + 1) & 1, t + 1);
            if (t & 1) STAGE_X(((t + 1) >> 1) & 1, (t + 1) >> 1);
        }

        const char* Xc = XL[(t >> 1) & 1];
        const char* Wc = WL[t & 1];
        bf16x8 xf[4], wf[4];
        #pragma unroll
        for (int st = 0; st < 4; ++st) {
            int row = wr * 64 + st * 16 + l15;
            int byte = (row * 128 + ((t & 1) * 4 + lg) * 16) ^ ((row & 7) << 4);
            xf[st] = *(const bf16x8*)(Xc + byte);
        }
        #pragma unroll
        for (int nt = 0; nt < 4; ++nt)
            wf[nt] = *(const bf16x8*)(Wc + lg * 2048
                                         + (wc * 64 + nt * 16 + l15) * 16);
        __builtin_amdgcn_s_setprio(1);
        #pragma unroll
        for (int nt = 0; nt < 4; ++nt)
            #pragma unroll
            for (int st = 0; st < 4; ++st)
                acc[nt][st] = __builtin_amdgcn_mfma_f32_16x16x32_bf16(
                                  wf[nt], xf[st], acc[nt][st], 0, 0, 0);
        __builtin_amdgcn_s_setprio(0);

        __syncthreads();             // next-step stages landed; reads retired
    }

    // ---- epilogue: activation -> per-wave LDS transpose -> 128B stores ----
    int gate    = ngt >> 1;                    // 0:z 1:f 2:o
    int ch_base = (ngt & 1) * 128 + wc * 64;   // channel base (0..255)
    _Float16* buf = (gate == 0) ? Zb : (gate == 1) ? Fb : Ob;
    char* Sw = (char*)XL + wid * 8192;         // 8KB per-wave scratch (32KB=XL)

    #pragma unroll
    for (int nt = 0; nt < 4; ++nt) {
        float4 bv = *(const float4*)(bias + ngt * 128 + wc * 64 + nt * 16 + lg * 4);
        #pragma unroll
        for (int st = 0; st < 4; ++st) {
            f16x4 hv;
            #pragma unroll
            for (int r = 0; r < 4; ++r) {
                float bvr = (r == 0) ? bv.x : (r == 1) ? bv.y : (r == 2) ? bv.z : bv.w;
                float y = acc[nt][st][r] + bvr;
                float v = (gate == 0) ? fast_tanh(y) : fast_sigmoid(y);
                hv[r] = (_Float16)v;
            }
            int byte = ((st * 16 + l15) * 128 + (nt * 16 + lg * 4) * 2)
                       ^ ((l15 & 7) << 4);
            *(f16x4*)(Sw + byte) = hv;
        }
    }
    #pragma unroll
    for (int so = 0; so < 16; ++so) {
        int s_loc = so * 4 + lg;
        int byte  = (s_loc * 128 + l15 * 8) ^ ((s_loc & 7) << 4);
        f16x4 v = *(const f16x4*)(Sw + byte);
        *(f16x4*)(buf + ((size_t)bi * SEQ + s0 + wr * 64 + s_loc) * CHN
                      + ch_base + l15 * 4) = v;
    }
}

// ---------------------------------------------------------------------------
// K2: per-chunk scan summaries; thread handles 2 channels (4B f16x2 loads).
// ---------------------------------------------------------------------------
__global__ __launch_bounds__(128) void k_scan1(const _Float16* __restrict__ Fb,
                                               const _Float16* __restrict__ Zb,
                                               float* __restrict__ Aq,
                                               float* __restrict__ Bq) {
    int bi = blockIdx.x >> 5;
    int ck = blockIdx.x & 31;
    int c2 = threadIdx.x;
    size_t base = (((size_t)bi * SEQ + ck * TS) * CHN + c2 * 2) >> 1;
    const f16x2* F2 = (const f16x2*)Fb;
    const f16x2* Z2 = (const f16x2*)Zb;
    float a0 = 1.f, a1 = 1.f, c0 = 0.f, c1 = 0.f;
    #pragma unroll 8
    for (int s = 0; s < TS; ++s) {
        f16x2 f = F2[base + (size_t)s * (CHN / 2)];
        f16x2 z = Z2[base + (size_t)s * (CHN / 2)];
        float f0 = (float)f[0], f1 = (float)f[1];
        c0 = f0 * c0 + (1.f - f0) * (float)z[0];
        c1 = f1 * c1 + (1.f - f1) * (float)z[1];
        a0 *= f0; a1 *= f1;
    }
    int o = blockIdx.x * CHN + c2 * 2;
    *(float2*)(Aq + o) = make_float2(a0, a1);
    *(float2*)(Bq + o) = make_float2(c0, c1);
}

// ---------------------------------------------------------------------------
// K3: sequential carry across chunks. 8 blocks x 256 threads, 32 steps.
// ---------------------------------------------------------------------------
__global__ __launch_bounds__(256) void k_scan2(const float* __restrict__ Aq,
                                               const float* __restrict__ Bq,
                                               float* __restrict__ Cq) {
    int bi = blockIdx.x;
    int ch = threadIdx.x;
    float c = 0.f;
    #pragma unroll
    for (int ck = 0; ck < NCHUNK; ++ck) {
        int o = (bi * NCHUNK + ck) * CHN + ch;
        Cq[o] = c;
        c = Aq[o] * c + Bq[o];
    }
}

// ---------------------------------------------------------------------------
// K4: final pass — redo local scan seeded with carry, out = sigmoid(o) * c.
// ---------------------------------------------------------------------------
__global__ __launch_bounds__(128) void k_scan3(const _Float16* __restrict__ Fb,
                                               const _Float16* __restrict__ Zb,
                                               const _Float16* __restrict__ Ob,
                                               const float* __restrict__ Cq,
                                               float* __restrict__ out) {
    int bi = blockIdx.x >> 5;
    int ck = blockIdx.x & 31;
    int c2 = threadIdx.x;
    float2 c = *(const float2*)(Cq + blockIdx.x * CHN + c2 * 2);
    size_t base = (((size_t)bi * SEQ + ck * TS) * CHN + c2 * 2) >> 1;
    const f16x2* F2 = (const f16x2*)Fb;
    const f16x2* Z2 = (const f16x2*)Zb;
    const f16x2* O2 = (const f16x2*)Ob;
    float* outp = out + (((size_t)bi * SEQ + ck * TS) * CHN + c2 * 2);
    #pragma unroll 4
    for (int s = 0; s < TS; ++s) {
        f16x2 f  = F2[base + (size_t)s * (CHN / 2)];
        f16x2 z  = Z2[base + (size_t)s * (CHN / 2)];
        f16x2 so = O2[base + (size_t)s * (CHN / 2)];
        float f0 = (float)f[0], f1 = (float)f[1];
        c.x = f0 * c.x + (1.f - f0) * (float)z[0];
        c.y = f1 * c.y + (1.f - f1) * (float)z[1];
        *(float2*)(outp + (size_t)s * CHN) = make_float2((float)so[0] * c.x,
                                                         (float)so[1] * c.y);
    }
}

// ---------------------------------------------------------------------------
extern "C" void kernel_launch(void* const* d_in, const int* in_sizes, int n_in,
                              void* d_out, int out_size, void* d_ws, size_t ws_size,
                              hipStream_t stream)
{
    const float* x = (const float*)d_in[0];   // (8,4096,256) fp32
    const float* W = (const float*)d_in[1];   // (768,512)    fp32
    const float* b = (const float*)d_in[2];   // (768,)       fp32
    float* out = (float*)d_out;               // (8,4096,256) fp32

    char* ws = (char*)d_ws;
    const size_t MB = 1024 * 1024;
    _Float16* Zb = (_Float16*)(ws +  0 * MB);   // 16 MB
    _Float16* Fb = (_Float16*)(ws + 16 * MB);   // 16 MB
    _Float16* Ob = (_Float16*)(ws + 32 * MB);   // 16 MB
    __bf16*   Wt = (__bf16*)  (ws + 48 * MB);   // 768 KB
    float*    Aq = (float*)   (ws + 49 * MB);   // 256 KB
    float*    Bq = (float*)   (ws + 50 * MB);   // 256 KB
    float*    Cq = (float*)   (ws + 51 * MB);   // 256 KB
    __bf16*   Xb = (__bf16*)  (ws + 52 * MB);   // 16.02 MB

    k_convW<<<dim3(192),            dim3(256), 0, stream>>>(W, Wt);
    k_convX<<<dim3(4096),           dim3(256), 0, stream>>>(x, Xb);
    k_gemm <<<dim3(1536),           dim3(256), 0, stream>>>(Xb, Wt, b, Zb, Fb, Ob);
    k_scan1<<<dim3(BATCH * NCHUNK), dim3(128), 0, stream>>>(Fb, Zb, Aq, Bq);
    k_scan2<<<dim3(BATCH),          dim3(256), 0, stream>>>(Aq, Bq, Cq);
    k_scan3<<<dim3(BATCH * NCHUNK), dim3(128), 0, stream>>>(Fb, Zb, Ob, Cq, out);
}